// Round 1
// baseline (627.772 us; speedup 1.0000x reference)
//
#include <hip/hip_runtime.h>
#include <math.h>

#define N 4096
#define IN_F 256
#define OUT_F 64
#define HEADS 4
#define NEG 0.2f

#define FMA4S(A, s, V) do { (A).x = fmaf((s),(V).x,(A).x); (A).y = fmaf((s),(V).y,(A).y); \
                            (A).z = fmaf((s),(V).z,(A).z); (A).w = fmaf((s),(V).w,(A).w); } while(0)

// ---------------------------------------------------------------------------
// Kernel 1: xt[h][n][f] = x[n][:] @ W[h][:][f]; src[h][n] = xt.a_src; dst = xt.a_dst
// grid (64, 4) = (n-tile of 64 rows, head), block 256.
// Thread (fg = t&15, rg = t>>4): rows rg*4+q (q=0..3), cols fg*4..fg*4+3.
// ---------------------------------------------------------------------------
__global__ __launch_bounds__(256) void k_xt(const float* __restrict__ x,
                                            const float* __restrict__ W,
                                            const float* __restrict__ a,
                                            float* __restrict__ xt,
                                            float* __restrict__ src,
                                            float* __restrict__ dst) {
  __shared__ __align__(16) float xls[64 * 68];  // pad 68: rg-groups land 16 banks apart (2-way = free)
  __shared__ __align__(16) float wls[64 * 64];
  const int t  = threadIdx.x;
  const int h  = blockIdx.y;
  const int i0 = blockIdx.x * 64;
  const int fg = t & 15;
  const int rg = t >> 4;

  float4 acc[4];
  acc[0] = acc[1] = acc[2] = acc[3] = make_float4(0.f, 0.f, 0.f, 0.f);

  const float4* xg = (const float4*)x;    // x row = 64 float4
  const float4* wg = (const float4*)W;    // W[h] row (per k) = 16 float4
  float4* xls4 = (float4*)xls;
  float4* wls4 = (float4*)wls;
  const float4* xr4 = (const float4*)xls;
  const float4* wr4 = (const float4*)wls;

  for (int kt = 0; kt < 4; ++kt) {
    __syncthreads();
    // stage x tile: 64 rows x 64 k  (rows i0.., cols kt*64..)
    #pragma unroll
    for (int s = 0; s < 4; ++s) {
      int f4i = t + 256 * s;              // 0..1023
      int row = f4i >> 4, c4 = f4i & 15;
      xls4[row * 17 + c4] = xg[(size_t)(i0 + row) * 64 + kt * 16 + c4];
    }
    // stage W tile: 64 k x 64 f (contiguous block of W[h])
    #pragma unroll
    for (int s = 0; s < 4; ++s) {
      int f4i = t + 256 * s;
      int kk = f4i >> 4, c4 = f4i & 15;
      wls4[kk * 16 + c4] = wg[(size_t)(h * 256 + kt * 64 + kk) * 16 + c4];
    }
    __syncthreads();
    #pragma unroll 4
    for (int kk = 0; kk < 64; kk += 4) {
      float4 wv0 = wr4[(kk + 0) * 16 + fg];
      float4 wv1 = wr4[(kk + 1) * 16 + fg];
      float4 wv2 = wr4[(kk + 2) * 16 + fg];
      float4 wv3 = wr4[(kk + 3) * 16 + fg];
      #pragma unroll
      for (int q = 0; q < 4; ++q) {
        float4 xv = xr4[(rg * 4 + q) * 17 + (kk >> 2)];
        FMA4S(acc[q], xv.x, wv0);
        FMA4S(acc[q], xv.y, wv1);
        FMA4S(acc[q], xv.z, wv2);
        FMA4S(acc[q], xv.w, wv3);
      }
    }
  }

  // write xt (coalesced: 16 lanes x 16B per rg group)
  float4* xtg = (float4*)xt;
  #pragma unroll
  for (int q = 0; q < 4; ++q) {
    int r = rg * 4 + q;
    xtg[((size_t)h * N + i0 + r) * 16 + fg] = acc[q];
  }

  // src/dst: per-row dot over f (16 fg lanes per row-group, shfl_xor reduce)
  const float4* a4 = (const float4*)a;    // a[h] = 32 float4 (16 src + 16 dst)
  float4 as = a4[h * 32 + fg];
  float4 ad = a4[h * 32 + 16 + fg];
  #pragma unroll
  for (int q = 0; q < 4; ++q) {
    float s_ = acc[q].x * as.x + acc[q].y * as.y + acc[q].z * as.z + acc[q].w * as.w;
    float d_ = acc[q].x * ad.x + acc[q].y * ad.y + acc[q].z * ad.z + acc[q].w * ad.w;
    #pragma unroll
    for (int off = 1; off < 16; off <<= 1) {
      s_ += __shfl_xor(s_, off, 64);
      d_ += __shfl_xor(d_, off, 64);
    }
    if (fg == 0) {
      int r = rg * 4 + q;
      src[h * N + i0 + r] = s_;
      dst[h * N + i0 + r] = d_;
    }
  }
}

// ---------------------------------------------------------------------------
// Kernel 2: per-row softmax stats m[h][i], l[h][i] (online, one adj pass)
// grid 4096 (one row), block 256.
// ---------------------------------------------------------------------------
__global__ __launch_bounds__(256) void k_ml(const int* __restrict__ adj,
                                            const float* __restrict__ src,
                                            const float* __restrict__ dst,
                                            float* __restrict__ mg,
                                            float* __restrict__ lg) {
  const int i = blockIdx.x;
  const int t = threadIdx.x;
  float sv[HEADS], m[HEADS], l[HEADS];
  #pragma unroll
  for (int h = 0; h < HEADS; ++h) { sv[h] = src[h * N + i]; m[h] = -1e30f; l[h] = 0.f; }
  const int* arow = adj + (size_t)i * N;
  for (int j = t; j < N; j += 256) {
    int av = arow[j];
    if (av > 0) {
      #pragma unroll
      for (int h = 0; h < HEADS; ++h) {
        float e = sv[h] + dst[h * N + j];
        e = e > 0.f ? e : NEG * e;
        if (e <= m[h]) {
          l[h] += __expf(e - m[h]);
        } else {
          l[h] = l[h] * __expf(m[h] - e) + 1.f;
          m[h] = e;
        }
      }
    }
  }
  // wave butterfly reduce of (m,l) per head
  #pragma unroll
  for (int h = 0; h < HEADS; ++h) {
    for (int off = 1; off < 64; off <<= 1) {
      float mo = __shfl_xor(m[h], off, 64);
      float lo = __shfl_xor(l[h], off, 64);
      float mn = fmaxf(m[h], mo);
      l[h] = l[h] * __expf(m[h] - mn) + lo * __expf(mo - mn);
      m[h] = mn;
    }
  }
  __shared__ float red[4][HEADS][2];
  int wid = t >> 6, lid = t & 63;
  if (lid == 0) {
    #pragma unroll
    for (int h = 0; h < HEADS; ++h) { red[wid][h][0] = m[h]; red[wid][h][1] = l[h]; }
  }
  __syncthreads();
  if (t < HEADS) {
    int h = t;
    float mm = red[0][h][0], ll = red[0][h][1];
    #pragma unroll
    for (int w = 1; w < 4; ++w) {
      float mo = red[w][h][0], lo = red[w][h][1];
      float mn = fmaxf(mm, mo);
      ll = ll * __expf(mm - mn) + lo * __expf(mo - mn);
      mm = mn;
    }
    mg[h * N + i] = mm;
    lg[h * N + i] = ll;
  }
}

// ---------------------------------------------------------------------------
// Kernel 3: PV. 16 rows/block (all 4 heads), block 256 = 4 waves (wave = head).
// Per j-tile of 128: compute p into LDS, then register-tiled fp32 "GEMM"
// [16 x 128] @ [128 x 64] per head, xt read from global (L2-resident, 4MB).
// grid 256.
// ---------------------------------------------------------------------------
__global__ __launch_bounds__(256) void k_pv(const int* __restrict__ adj,
                                            const float* __restrict__ dst,
                                            const float* __restrict__ xt,
                                            const float* __restrict__ src,
                                            const float* __restrict__ mg,
                                            const float* __restrict__ lg,
                                            float* __restrict__ out) {
  __shared__ __align__(16) float p_s[HEADS][16][132];  // stride 132: rg groups 2-way (free)
  __shared__ float src_s[HEADS][16], m_s[HEADS][16], il_s[HEADS][16];
  const int t  = threadIdx.x;
  const int i0 = blockIdx.x * 16;
  if (t < 64) {
    int h = t >> 4, r = t & 15;
    src_s[h][r] = src[h * N + i0 + r];
    m_s[h][r]   = mg[h * N + i0 + r];
    il_s[h][r]  = 1.f / lg[h * N + i0 + r];
  }
  const int h    = t >> 6;   // wave id = head
  const int lane = t & 63;
  const int rg   = lane >> 4;
  const int fg   = lane & 15;
  const int jj   = t & 127;  // logit-phase column
  const int rh   = t >> 7;   // logit-phase row half
  float4 acc[4];
  acc[0] = acc[1] = acc[2] = acc[3] = make_float4(0.f, 0.f, 0.f, 0.f);
  const float4* xt4 = (const float4*)xt;
  __syncthreads();

  for (int jt = 0; jt < 32; ++jt) {
    const int j0 = jt * 128;
    // ---- logit phase: p[h][r][jj] for 16 rows x 128 cols ----
    float dv[HEADS];
    #pragma unroll
    for (int h2 = 0; h2 < HEADS; ++h2) dv[h2] = dst[h2 * N + j0 + jj];
    #pragma unroll 2
    for (int rr = 0; rr < 8; ++rr) {
      int r = rh * 8 + rr;
      int av = adj[(size_t)(i0 + r) * N + j0 + jj];
      if (av > 0) {
        #pragma unroll
        for (int h2 = 0; h2 < HEADS; ++h2) {
          float e = src_s[h2][r] + dv[h2];
          e = e > 0.f ? e : NEG * e;
          p_s[h2][r][jj] = __expf(e - m_s[h2][r]) * il_s[h2][r];
        }
      } else {
        #pragma unroll
        for (int h2 = 0; h2 < HEADS; ++h2) p_s[h2][r][jj] = 0.f;
      }
    }
    __syncthreads();
    // ---- PV phase: acc[q] += p[h][rg*4+q][:] * xt[h][j0+:][fg*4..] ----
    #pragma unroll 4
    for (int jc = 0; jc < 128; jc += 4) {
      float4 xv0 = xt4[((size_t)h * N + j0 + jc + 0) * 16 + fg];
      float4 xv1 = xt4[((size_t)h * N + j0 + jc + 1) * 16 + fg];
      float4 xv2 = xt4[((size_t)h * N + j0 + jc + 2) * 16 + fg];
      float4 xv3 = xt4[((size_t)h * N + j0 + jc + 3) * 16 + fg];
      #pragma unroll
      for (int q = 0; q < 4; ++q) {
        const float4 pv = *(const float4*)&p_s[h][rg * 4 + q][jc];
        FMA4S(acc[q], pv.x, xv0);
        FMA4S(acc[q], pv.y, xv1);
        FMA4S(acc[q], pv.z, xv2);
        FMA4S(acc[q], pv.w, xv3);
      }
    }
    __syncthreads();
  }

  // epilogue: out[i][h*64+f]
  float4* o4 = (float4*)out;
  #pragma unroll
  for (int q = 0; q < 4; ++q) {
    int r = rg * 4 + q;
    o4[(size_t)(i0 + r) * 64 + h * 16 + fg] = acc[q];
  }
}

extern "C" void kernel_launch(void* const* d_in, const int* in_sizes, int n_in,
                              void* d_out, int out_size, void* d_ws, size_t ws_size,
                              hipStream_t stream) {
  const float* x   = (const float*)d_in[0];
  const float* W   = (const float*)d_in[1];
  const float* a   = (const float*)d_in[2];
  const int*   adj = (const int*)d_in[3];
  float* out = (float*)d_out;

  float* ws  = (float*)d_ws;
  float* xt  = ws;                                  // HEADS*N*OUT_F = 1048576 floats
  float* src = xt + (size_t)HEADS * N * OUT_F;      // HEADS*N
  float* dst = src + HEADS * N;
  float* mg  = dst + HEADS * N;
  float* lg  = mg + HEADS * N;

  k_xt<<<dim3(64, 4), 256, 0, stream>>>(x, W, a, xt, src, dst);
  k_ml<<<dim3(N), 256, 0, stream>>>(adj, src, dst, mg, lg);
  k_pv<<<dim3(N / 16), 256, 0, stream>>>(adj, dst, xt, src, mg, lg, out);
}

// Round 2
// 157.329 us; speedup vs baseline: 3.9902x; 3.9902x over previous
//
#include <hip/hip_runtime.h>
#include <math.h>

#define N 4096
#define IN_F 256
#define OUT_F 64
#define HEADS 4
#define NEG 0.2f
#define JSPLIT 4

typedef float f32x4 __attribute__((ext_vector_type(4)));
typedef short short8 __attribute__((ext_vector_type(8)));

#define FMA4S(A, s, V) do { (A).x = fmaf((s),(V).x,(A).x); (A).y = fmaf((s),(V).y,(A).y); \
                            (A).z = fmaf((s),(V).z,(A).z); (A).w = fmaf((s),(V).w,(A).w); } while(0)

__device__ __forceinline__ unsigned short f2bf(float x) {
  unsigned int u = __float_as_uint(x);
  u += 0x7fffu + ((u >> 16) & 1u);   // RNE; inputs here are finite non-NaN
  return (unsigned short)(u >> 16);
}

// ---------------------------------------------------------------------------
// Kernel 1: xt = x @ W[h] (64-row tile per block), then:
//   - src/dst row dots (shfl-reduced)
//   - xtB: bf16 copy of xt in MFMA B-fragment layout:
//       xtB[h][jc][g][lane][r] = xt[jc*32 + (lane>>4)*8 + r][g*16 + (lane&15)]
// grid (64, 4) = (row-tile, head), block 256.
// ---------------------------------------------------------------------------
__global__ __launch_bounds__(256) void k_xt(const float* __restrict__ x,
                                            const float* __restrict__ W,
                                            const float* __restrict__ a,
                                            short* __restrict__ xtB,
                                            float* __restrict__ src,
                                            float* __restrict__ dst) {
  __shared__ __align__(16) float xls[64 * 68];
  __shared__ __align__(16) float wls[64 * 64];
  const int t  = threadIdx.x;
  const int h  = blockIdx.y;
  const int i0 = blockIdx.x * 64;
  const int fg = t & 15;
  const int rg = t >> 4;

  float4 acc[4];
  acc[0] = acc[1] = acc[2] = acc[3] = make_float4(0.f, 0.f, 0.f, 0.f);

  const float4* xg = (const float4*)x;
  const float4* wg = (const float4*)W;
  float4* xls4 = (float4*)xls;
  float4* wls4 = (float4*)wls;
  const float4* xr4 = (const float4*)xls;
  const float4* wr4 = (const float4*)wls;

  for (int kt = 0; kt < 4; ++kt) {
    __syncthreads();
    #pragma unroll
    for (int s = 0; s < 4; ++s) {
      int f4i = t + 256 * s;
      int row = f4i >> 4, c4 = f4i & 15;
      xls4[row * 17 + c4] = xg[(size_t)(i0 + row) * 64 + kt * 16 + c4];
    }
    #pragma unroll
    for (int s = 0; s < 4; ++s) {
      int f4i = t + 256 * s;
      int kk = f4i >> 4, c4 = f4i & 15;
      wls4[kk * 16 + c4] = wg[(size_t)(h * 256 + kt * 64 + kk) * 16 + c4];
    }
    __syncthreads();
    #pragma unroll 4
    for (int kk = 0; kk < 64; kk += 4) {
      float4 wv0 = wr4[(kk + 0) * 16 + fg];
      float4 wv1 = wr4[(kk + 1) * 16 + fg];
      float4 wv2 = wr4[(kk + 2) * 16 + fg];
      float4 wv3 = wr4[(kk + 3) * 16 + fg];
      #pragma unroll
      for (int q = 0; q < 4; ++q) {
        float4 xv = xr4[(rg * 4 + q) * 17 + (kk >> 2)];
        FMA4S(acc[q], xv.x, wv0);
        FMA4S(acc[q], xv.y, wv1);
        FMA4S(acc[q], xv.z, wv2);
        FMA4S(acc[q], xv.w, wv3);
      }
    }
  }

  // src/dst from register accumulators
  const float4* a4 = (const float4*)a;
  float4 as = a4[h * 32 + fg];
  float4 ad = a4[h * 32 + 16 + fg];
  #pragma unroll
  for (int q = 0; q < 4; ++q) {
    float s_ = acc[q].x * as.x + acc[q].y * as.y + acc[q].z * as.z + acc[q].w * as.w;
    float d_ = acc[q].x * ad.x + acc[q].y * ad.y + acc[q].z * ad.z + acc[q].w * ad.w;
    #pragma unroll
    for (int off = 1; off < 16; off <<= 1) {
      s_ += __shfl_xor(s_, off, 64);
      d_ += __shfl_xor(d_, off, 64);
    }
    if (fg == 0) {
      int r = rg * 4 + q;
      src[h * N + i0 + r] = s_;
      dst[h * N + i0 + r] = d_;
    }
  }

  // restage acc into xls (stride 68) for the B-fragment transpose/pack
  __syncthreads();
  #pragma unroll
  for (int q = 0; q < 4; ++q) {
    *(float4*)&xls[(rg * 4 + q) * 68 + fg * 4] = acc[q];
  }
  __syncthreads();

  {
    const int lane = t & 63;
    const int g    = t >> 6;        // col-group 0..3
    const int q    = lane >> 4;     // k-quad
    const int m    = lane & 15;     // B col within group
    short8* xb8 = (short8*)xtB;
    #pragma unroll
    for (int jcl = 0; jcl < 2; ++jcl) {
      int jc = (i0 >> 5) + jcl;
      short8 bv;
      #pragma unroll
      for (int r = 0; r < 8; ++r) {
        bv[r] = (short)f2bf(xls[(jcl * 32 + q * 8 + r) * 68 + g * 16 + m]);
      }
      xb8[((size_t)(h * 128 + jc) * 4 + g) * 64 + lane] = bv;
    }
  }
}

// ---------------------------------------------------------------------------
// Kernel 2: zero the accumulation workspace (accG + lG).
// ---------------------------------------------------------------------------
__global__ __launch_bounds__(256) void k_zero(float4* __restrict__ p, int n4) {
  int i = blockIdx.x * 256 + threadIdx.x;
  if (i < n4) p[i] = make_float4(0.f, 0.f, 0.f, 0.f);
}

// ---------------------------------------------------------------------------
// Kernel 3: fused flash PV (no max subtraction; logits are bounded).
// grid (128, JSPLIT): blockIdx.x -> i0 = bx*32 (two 16-row MFMA tiles),
// blockIdx.y -> j-range split. Block 256 = 4 waves; wave w = head w.
// Per 32-j chunk: build P (bf16 A-frags) from adj/src/dst, 8x mfma 16x16x32,
// accumulate row sums l. Epilogue: fp32 atomicAdd into accG/lG.
// ---------------------------------------------------------------------------
__global__ __launch_bounds__(256) void k_flash(const int* __restrict__ adj,
                                               const float* __restrict__ src,
                                               const float* __restrict__ dst,
                                               const short* __restrict__ xtB,
                                               float* __restrict__ accG,
                                               float* __restrict__ lG) {
  const int t    = threadIdx.x;
  const int lane = t & 63;
  const int h    = t >> 6;            // wave = head
  const int i0   = blockIdx.x * 32;
  const int js   = blockIdx.y;
  const int q    = lane >> 4;         // k-quad
  const int m    = lane & 15;         // row within 16-tile / accum col
  const int koff = q * 8;

  // src values for this lane's two rows (tile0: i0+m, tile1: i0+16+m)
  float sv = (lane < 32) ? src[h * N + i0 + lane] : 0.f;
  const float s0 = __shfl(sv, m, 64);
  const float s1 = __shfl(sv, 16 + m, 64);

  f32x4 acc0[4], acc1[4];
  #pragma unroll
  for (int g = 0; g < 4; ++g) { acc0[g] = (f32x4)(0.f); acc1[g] = (f32x4)(0.f); }
  float l0 = 0.f, l1 = 0.f;

  const short8* xb8 = (const short8*)xtB;
  const int jbase = js * (N / JSPLIT);

  for (int c = 0; c < (N / JSPLIT) / 32; ++c) {
    const int j0 = jbase + c * 32;

    // dst[j0+koff .. +8) for this head
    union { float4 v[2]; float f[8]; } du;
    du.v[0] = *(const float4*)(dst + h * N + j0 + koff);
    du.v[1] = *(const float4*)(dst + h * N + j0 + koff + 4);

    // adj rows for the two 16-row tiles
    union { int4 v[2]; int i[8]; } ad0, ad1;
    const int* r0 = adj + (size_t)(i0 + m) * N + j0 + koff;
    const int* r1 = adj + (size_t)(i0 + 16 + m) * N + j0 + koff;
    ad0.v[0] = *(const int4*)r0;  ad0.v[1] = *(const int4*)(r0 + 4);
    ad1.v[0] = *(const int4*)r1;  ad1.v[1] = *(const int4*)(r1 + 4);

    // B fragments (4 col-groups)
    short8 b0 = xb8[((size_t)(h * 128 + (j0 >> 5)) * 4 + 0) * 64 + lane];
    short8 b1 = xb8[((size_t)(h * 128 + (j0 >> 5)) * 4 + 1) * 64 + lane];
    short8 b2 = xb8[((size_t)(h * 128 + (j0 >> 5)) * 4 + 2) * 64 + lane];
    short8 b3 = xb8[((size_t)(h * 128 + (j0 >> 5)) * 4 + 3) * 64 + lane];

    // P fragments
    short8 a0, a1;
    #pragma unroll
    for (int r = 0; r < 8; ++r) {
      float e0 = s0 + du.f[r];
      e0 = fmaxf(e0, NEG * e0);
      float p0 = (ad0.i[r] > 0) ? __expf(e0) : 0.f;
      l0 += p0;
      a0[r] = (short)f2bf(p0);
      float e1 = s1 + du.f[r];
      e1 = fmaxf(e1, NEG * e1);
      float p1 = (ad1.i[r] > 0) ? __expf(e1) : 0.f;
      l1 += p1;
      a1[r] = (short)f2bf(p1);
    }

    acc0[0] = __builtin_amdgcn_mfma_f32_16x16x32_bf16(a0, b0, acc0[0], 0, 0, 0);
    acc0[1] = __builtin_amdgcn_mfma_f32_16x16x32_bf16(a0, b1, acc0[1], 0, 0, 0);
    acc0[2] = __builtin_amdgcn_mfma_f32_16x16x32_bf16(a0, b2, acc0[2], 0, 0, 0);
    acc0[3] = __builtin_amdgcn_mfma_f32_16x16x32_bf16(a0, b3, acc0[3], 0, 0, 0);
    acc1[0] = __builtin_amdgcn_mfma_f32_16x16x32_bf16(a1, b0, acc1[0], 0, 0, 0);
    acc1[1] = __builtin_amdgcn_mfma_f32_16x16x32_bf16(a1, b1, acc1[1], 0, 0, 0);
    acc1[2] = __builtin_amdgcn_mfma_f32_16x16x32_bf16(a1, b2, acc1[2], 0, 0, 0);
    acc1[3] = __builtin_amdgcn_mfma_f32_16x16x32_bf16(a1, b3, acc1[3], 0, 0, 0);
  }

  // ---- epilogue ----
  // l: sum the 4 k-quads (lanes m, m^16, m^32, m^48)
  l0 += __shfl_xor(l0, 16, 64);  l0 += __shfl_xor(l0, 32, 64);
  l1 += __shfl_xor(l1, 16, 64);  l1 += __shfl_xor(l1, 32, 64);
  if (lane < 16) {
    atomicAdd(&lG[h * N + i0 + lane], l0);
    atomicAdd(&lG[h * N + i0 + 16 + lane], l1);
  }

  // acc: C layout col = lane&15, row = (lane>>4)*4 + reg
  #pragma unroll
  for (int reg = 0; reg < 4; ++reg) {
    int row0 = i0 + q * 4 + reg;
    int row1 = row0 + 16;
    #pragma unroll
    for (int g = 0; g < 4; ++g) {
      atomicAdd(&accG[((size_t)h * N + row0) * 64 + g * 16 + m], acc0[g][reg]);
      atomicAdd(&accG[((size_t)h * N + row1) * 64 + g * 16 + m], acc1[g][reg]);
    }
  }
}

// ---------------------------------------------------------------------------
// Kernel 4: out[i][h*64+f] = accG[h][i][f] / lG[h][i]
// ---------------------------------------------------------------------------
__global__ __launch_bounds__(256) void k_div(const float* __restrict__ accG,
                                             const float* __restrict__ lG,
                                             float* __restrict__ out) {
  int v = blockIdx.x * 256 + threadIdx.x;   // over N*64 float4s
  int col4 = v & 63;                         // 64 float4 per out row
  int i    = v >> 6;
  int h    = col4 >> 4;
  int fg   = col4 & 15;
  const float4* a4 = (const float4*)accG;
  float4 av = a4[((size_t)h * N + i) * 16 + fg];
  float il = 1.f / lG[h * N + i];
  float4 ov = make_float4(av.x * il, av.y * il, av.z * il, av.w * il);
  ((float4*)out)[v] = ov;
}

extern "C" void kernel_launch(void* const* d_in, const int* in_sizes, int n_in,
                              void* d_out, int out_size, void* d_ws, size_t ws_size,
                              hipStream_t stream) {
  const float* x   = (const float*)d_in[0];
  const float* W   = (const float*)d_in[1];
  const float* a   = (const float*)d_in[2];
  const int*   adj = (const int*)d_in[3];
  float* out = (float*)d_out;

  float* ws   = (float*)d_ws;
  short* xtB  = (short*)ws;                         // H*128*4*64*8 bf16 = 524288 floats worth
  float* src  = ws + 524288;                        // H*N
  float* dst  = src + HEADS * N;                    // H*N
  float* accG = dst + HEADS * N;                    // H*N*64
  float* lG   = accG + (size_t)HEADS * N * OUT_F;   // H*N

  const int zero_n4 = (HEADS * N * OUT_F + HEADS * N) / 4;   // accG + lG contiguous
  k_zero<<<dim3((zero_n4 + 255) / 256), 256, 0, stream>>>((float4*)accG, zero_n4);
  k_xt<<<dim3(64, 4), 256, 0, stream>>>(x, W, a, xtB, src, dst);
  k_flash<<<dim3(128, JSPLIT), 256, 0, stream>>>(adj, src, dst, xtB, accG, lG);
  k_div<<<dim3((N * OUT_F) / 256), 256, 0, stream>>>(accG, lG, out);
}